// Round 4
// baseline (165.653 us; speedup 1.0000x reference)
//
#include <hip/hip_runtime.h>
#include <math.h>

#define BSZ 4096
#define D 128
#define NCLS 64
#define MARGIN_F 1.0f

// ---- all scratch in device globals: no d_ws usage, no OOB risk, graph-safe ----
__device__ float g_mag[BSZ];
__device__ float g_row_neg[BSZ];
__device__ float g_acc;
__device__ int   g_hist[NCLS];
__device__ int   g_offs[NCLS];
__device__ int   g_cursor[NCLS];
__device__ int   g_counter;
__device__ int   g_order[BSZ];

// ---------------- init: zero everything we accumulate into ----------------
__global__ void init_kernel() {
    int i = blockIdx.x * 256 + threadIdx.x;
    if (i < BSZ) g_row_neg[i] = 0.0f;
    if (i < NCLS) { g_hist[i] = 0; g_cursor[i] = 0; }
    if (i == 0) g_acc = 0.0f;
}

// ---------------- mag + label histogram ----------------
__global__ void maghist_kernel(const float* __restrict__ X, const int* __restrict__ T) {
    int i = blockIdx.x * 256 + threadIdx.x;
    if (i >= BSZ) return;
    const float4* row = (const float4*)(X + (size_t)i * D);
    float m = 0.0f;
#pragma unroll
    for (int k = 0; k < D / 4; ++k) {
        float4 v = row[k];
        m += v.x * v.x + v.y * v.y + v.z * v.z + v.w * v.w;
    }
    g_mag[i] = m;
    atomicAdd(&g_hist[T[i]], 1);
}

// ---------------- row_neg: symmetric tiled Gram + masked exp row/col sums ----------------
// Block (bi,bj) with bj>=bi computes the 64x64 tile once. Row-sums go to rows bi*64+gi;
// for strictly-off-diagonal tiles, column-sums (== symmetric row-sums) go to rows bj*64+gj.
__global__ __launch_bounds__(256) void rowneg_kernel(const float* __restrict__ X,
                                                     const int* __restrict__ T) {
    const int bi = blockIdx.y;    // row tile
    const int bj = blockIdx.x;    // col tile
    if (bj < bi) return;          // uniform early exit, before any barrier

    __shared__ float As[D][64];   // 32 KB, k-major
    __shared__ float Bs[D][64];   // 32 KB, k-major
    __shared__ float magA[64], magB[64];
    __shared__ int   labA[64], labB[64];
    __shared__ float red[64][17]; // padded reduce buffer (reused row then col)

    const int tid = threadIdx.x;

    // staging: thread (r, q) loads 8 float4 (32 k's) of row r for A and B
    const int r = tid >> 2, q = tid & 3;
    const float4* Arow = (const float4*)(X + (size_t)(bi * 64 + r) * D + q * 32);
    const float4* Brow = (const float4*)(X + (size_t)(bj * 64 + r) * D + q * 32);
#pragma unroll
    for (int m = 0; m < 8; ++m) {
        int k = q * 32 + m * 4;
        float4 a = Arow[m];
        As[k + 0][r] = a.x; As[k + 1][r] = a.y; As[k + 2][r] = a.z; As[k + 3][r] = a.w;
        float4 b = Brow[m];
        Bs[k + 0][r] = b.x; Bs[k + 1][r] = b.y; Bs[k + 2][r] = b.z; Bs[k + 3][r] = b.w;
    }
    if (tid < 64) { magA[tid] = g_mag[bi * 64 + tid]; labA[tid] = T[bi * 64 + tid]; }
    else if (tid < 128) { int u = tid - 64; magB[u] = g_mag[bj * 64 + u]; labB[u] = T[bj * 64 + u]; }
    __syncthreads();

    const int tx = tid & 15, ty = tid >> 4;
    float s[4][4] = {{0.f,0.f,0.f,0.f},{0.f,0.f,0.f,0.f},{0.f,0.f,0.f,0.f},{0.f,0.f,0.f,0.f}};
#pragma unroll 4
    for (int k = 0; k < D; ++k) {
        float4 a = *(const float4*)&As[k][ty * 4];
        float4 b = *(const float4*)&Bs[k][tx * 4];
        s[0][0] = fmaf(a.x, b.x, s[0][0]); s[0][1] = fmaf(a.x, b.y, s[0][1]);
        s[0][2] = fmaf(a.x, b.z, s[0][2]); s[0][3] = fmaf(a.x, b.w, s[0][3]);
        s[1][0] = fmaf(a.y, b.x, s[1][0]); s[1][1] = fmaf(a.y, b.y, s[1][1]);
        s[1][2] = fmaf(a.y, b.z, s[1][2]); s[1][3] = fmaf(a.y, b.w, s[1][3]);
        s[2][0] = fmaf(a.z, b.x, s[2][0]); s[2][1] = fmaf(a.z, b.y, s[2][1]);
        s[2][2] = fmaf(a.z, b.z, s[2][2]); s[2][3] = fmaf(a.z, b.w, s[2][3]);
        s[3][0] = fmaf(a.w, b.x, s[3][0]); s[3][1] = fmaf(a.w, b.y, s[3][1]);
        s[3][2] = fmaf(a.w, b.z, s[3][2]); s[3][3] = fmaf(a.w, b.w, s[3][3]);
    }

    // masked exp terms; accumulate row partials rp and col partials cp
    float rp[4] = {0.f, 0.f, 0.f, 0.f};
    float cp[4] = {0.f, 0.f, 0.f, 0.f};
#pragma unroll
    for (int rr = 0; rr < 4; ++rr) {
        int gi = ty * 4 + rr;
        int li = labA[gi];
        float mi = magA[gi];
#pragma unroll
        for (int cc = 0; cc < 4; ++cc) {
            int gj = tx * 4 + cc;
            if (labB[gj] != li) {
                float d2 = fmaxf(mi + magB[gj] - 2.0f * s[rr][cc], 0.0f);
                float t = __expf(MARGIN_F - sqrtf(d2));
                rp[rr] += t;
                cp[cc] += t;
            }
        }
    }

    // row reduce: red[row gi][tx]
#pragma unroll
    for (int rr = 0; rr < 4; ++rr) red[ty * 4 + rr][tx] = rp[rr];
    __syncthreads();
    if (tid < 64) {
        float sum = 0.0f;
#pragma unroll
        for (int x2 = 0; x2 < 16; ++x2) sum += red[tid][x2];
        atomicAdd(&g_row_neg[bi * 64 + tid], sum);
    }
    __syncthreads();   // red reused below

    if (bj > bi) {
        // col reduce: red[col gj][ty]
#pragma unroll
        for (int cc = 0; cc < 4; ++cc) red[tx * 4 + cc][ty] = cp[cc];
        __syncthreads();
        if (tid < 64) {
            float sum = 0.0f;
#pragma unroll
            for (int y2 = 0; y2 < 16; ++y2) sum += red[tid][y2];
            atomicAdd(&g_row_neg[bj * 64 + tid], sum);
        }
    }
}

// ---------------- prefix offsets + positive-pair counter (wave64 scan) ----------------
__global__ void prefix_kernel() {
    int c = threadIdx.x;          // 64 threads
    int n = g_hist[c];
    int x = n;
#pragma unroll
    for (int off = 1; off < 64; off <<= 1) {
        int y = __shfl_up(x, off);
        if (c >= off) x += y;
    }
    g_offs[c] = x - n;            // exclusive prefix
    int p = n * (n - 1) / 2;
#pragma unroll
    for (int off = 32; off > 0; off >>= 1) p += __shfl_down(p, off);
    if (c == 0) g_counter = p;
}

// ---------------- scatter indices grouped by class ----------------
__global__ void scatter_kernel(const int* __restrict__ T) {
    int i = blockIdx.x * 256 + threadIdx.x;
    if (i >= BSZ) return;
    int c = T[i];
    int p = atomicAdd(&g_cursor[c], 1);
    g_order[g_offs[c] + p] = i;
}

// ---------------- positive-pair hinge loss ----------------
__global__ __launch_bounds__(256) void loss_kernel(const float* __restrict__ X) {
    const int c = blockIdx.x;
    const int n = g_hist[c];
    const int base = g_offs[c];
    const long long P = (long long)n * (n - 1) / 2;
    float lacc = 0.0f;

    for (long long p = threadIdx.x + (long long)blockIdx.y * 256; p < P; p += 1024) {
        // decode (a,b), a<b, from linear upper-triangular index p
        float nf = (float)n;
        float pf = (float)p;
        int a = (int)((nf - 0.5f) - sqrtf((nf - 0.5f) * (nf - 0.5f) - 2.0f * pf));
        if (a < 0) a = 0;
        if (a > n - 2) a = n - 2;
        auto cum = [&](int aa) -> long long {
            return (long long)aa * (n - 1) - (long long)aa * (aa - 1) / 2;
        };
        while (cum(a + 1) <= p) ++a;
        while (cum(a) > p) --a;
        int b = (int)(p - cum(a)) + a + 1;

        int ia = g_order[base + a], ib = g_order[base + b];
        const float4* xa = (const float4*)(X + (size_t)ia * D);
        const float4* xb = (const float4*)(X + (size_t)ib * D);
        float dot = 0.0f;
#pragma unroll
        for (int k = 0; k < D / 4; ++k) {
            float4 u = xa[k]; float4 v = xb[k];
            dot += u.x * v.x + u.y * v.y + u.z * v.z + u.w * v.w;
        }
        float d2 = fmaxf(g_mag[ia] + g_mag[ib] - 2.0f * dot, 0.0f);
        float dist = sqrtf(d2);
        float ln = logf(g_row_neg[ia] + g_row_neg[ib]);
        float h = fmaxf(ln + dist, 0.0f);
        lacc += h * h;
    }

    // wave then block reduce
    for (int off = 32; off > 0; off >>= 1) lacc += __shfl_down(lacc, off);
    __shared__ float warp_s[4];
    int lane = threadIdx.x & 63, w = threadIdx.x >> 6;
    if (lane == 0) warp_s[w] = lacc;
    __syncthreads();
    if (threadIdx.x == 0) atomicAdd(&g_acc, warp_s[0] + warp_s[1] + warp_s[2] + warp_s[3]);
}

// ---------------- final scalar ----------------
__global__ void final_kernel(float* __restrict__ out) {
    if (threadIdx.x == 0) out[0] = g_acc / (2.0f * (float)g_counter);
}

extern "C" void kernel_launch(void* const* d_in, const int* in_sizes, int n_in,
                              void* d_out, int out_size, void* d_ws, size_t ws_size,
                              hipStream_t stream) {
    const float* X = (const float*)d_in[0];
    const int* T = (const int*)d_in[1];
    float* out = (float*)d_out;
    (void)d_ws; (void)ws_size;

    init_kernel<<<dim3(16), dim3(256), 0, stream>>>();
    maghist_kernel<<<dim3(16), dim3(256), 0, stream>>>(X, T);
    rowneg_kernel<<<dim3(64, 64), dim3(256), 0, stream>>>(X, T);
    prefix_kernel<<<dim3(1), dim3(64), 0, stream>>>();
    scatter_kernel<<<dim3(16), dim3(256), 0, stream>>>(T);
    loss_kernel<<<dim3(64, 4), dim3(256), 0, stream>>>(X);
    final_kernel<<<dim3(1), dim3(64), 0, stream>>>(out);
}

// Round 5
// 109.049 us; speedup vs baseline: 1.5191x; 1.5191x over previous
//
#include <hip/hip_runtime.h>
#include <math.h>

#define BSZ 4096
#define D 128
#define NCLS 64
#define MARGIN_F 1.0f
#define LOSS_BLOCKS 256

typedef short bf16x8 __attribute__((ext_vector_type(8)));
typedef float f32x4  __attribute__((ext_vector_type(4)));

// ---- all scratch in device globals: no d_ws usage, graph-safe, re-inited every call ----
__device__ float g_row_neg[BSZ];
__device__ float g_acc;
__device__ int   g_hist[NCLS];
__device__ int   g_offs[NCLS];
__device__ int   g_counter;
__device__ int   g_order[BSZ];
__device__ int   g_done;

__device__ __forceinline__ unsigned short f2bf(float x) {
    union { float f; unsigned int u; } v; v.f = x;
    unsigned int u = v.u;
    return (unsigned short)((u + 0x7FFFu + ((u >> 16) & 1u)) >> 16);   // RNE
}
__device__ __forceinline__ float bf2f(unsigned short b) {
    union { unsigned int u; float f; } v; v.u = ((unsigned int)b) << 16;
    return v.f;
}

// ---------------- prep: zero accumulators + hist + scan + scatter (1 block) ----------------
__global__ __launch_bounds__(1024) void prep_kernel(const int* __restrict__ T) {
    __shared__ int h[NCLS], cur[NCLS];
    const int tid = threadIdx.x;
#pragma unroll
    for (int j = 0; j < 4; ++j) g_row_neg[tid + j * 1024] = 0.0f;
    if (tid == 0) { g_acc = 0.0f; g_done = 0; }
    if (tid < NCLS) h[tid] = 0;
    __syncthreads();
#pragma unroll
    for (int j = 0; j < 4; ++j) atomicAdd(&h[T[tid + j * 1024]], 1);
    __syncthreads();
    if (tid < 64) {                       // wave 0: scan + pair counter
        int n = h[tid];
        int x = n;
#pragma unroll
        for (int off = 1; off < 64; off <<= 1) {
            int y = __shfl_up(x, off);
            if (tid >= off) x += y;
        }
        g_offs[tid] = x - n; g_hist[tid] = n; cur[tid] = x - n;
        int p = n * (n - 1) / 2;
#pragma unroll
        for (int off = 32; off > 0; off >>= 1) p += __shfl_down(p, off);
        if (tid == 0) g_counter = p;
    }
    __syncthreads();
#pragma unroll
    for (int j = 0; j < 4; ++j) {
        int i = tid + j * 1024;
        int c = T[i];
        int p = atomicAdd(&cur[c], 1);
        g_order[p] = i;
    }
}

// ---------------- row_neg: bf16 MFMA symmetric tiled Gram + masked exp row/col sums ----------
// Block (bi,bj), bj>=bi, computes the 64x64 tile via mfma_f32_16x16x32_bf16.
// LDS tiles: bf16 row-major [64][128] with 16B-chunk XOR swizzle (chunk ^ (row&7)) so the
// 16-lane stride-256B ds_read_b128 fragment reads are bank-conflict-free (2-way max).
// A and B fragments use IDENTICAL lane patterns, so any k-permutation in the HW frag
// layout cancels in A*A^T. C/D layout: col=lane&15, row=(lane>>4)*4+reg (m89-verified).
__global__ __launch_bounds__(256) void rowneg_kernel(const float* __restrict__ X,
                                                     const int* __restrict__ T) {
    const int bi = blockIdx.y, bj = blockIdx.x;
    if (bj < bi) return;   // block-uniform exit before any barrier

    __shared__ __align__(16) unsigned short Ab[64 * 128];  // 16 KB
    __shared__ __align__(16) unsigned short Bb[64 * 128];  // 16 KB
    __shared__ float rowred[64][33];                       // 8.25 KB (pad 33 vs bank conflicts)
    __shared__ float colred[64][9];                        // 2.25 KB
    __shared__ float magA[64], magB[64];
    __shared__ int   labA[64], labB[64];

    const int tid = threadIdx.x;
    const int biBase = bi * 64, bjBase = bj * 64;

    // ---- stage A,B tiles: linear f32->bf16 copy, swizzled 8B LDS writes ----
    {
        const float4* GA = (const float4*)(X + (size_t)biBase * D);
        const float4* GB = (const float4*)(X + (size_t)bjBase * D);
#pragma unroll
        for (int j = 0; j < 8; ++j) {
            int idx = tid + j * 256;            // 0..2047 linear float4 index (coalesced)
            int row = idx >> 5, f4 = idx & 31;
            int c = f4 >> 1, hh = f4 & 1;
            int byteoff = row * 256 + ((c ^ (row & 7)) << 4) + (hh << 3);
            float4 a = GA[idx];
            ushort4 pa = make_ushort4(f2bf(a.x), f2bf(a.y), f2bf(a.z), f2bf(a.w));
            *(ushort4*)((char*)Ab + byteoff) = pa;
            float4 b = GB[idx];
            ushort4 pb = make_ushort4(f2bf(b.x), f2bf(b.y), f2bf(b.z), f2bf(b.w));
            *(ushort4*)((char*)Bb + byteoff) = pb;
        }
    }
    if (tid >= 128 && tid < 192) labA[tid - 128] = T[biBase + tid - 128];
    if (tid >= 192)              labB[tid - 192] = T[bjBase + tid - 192];
    __syncthreads();

    // ---- per-row squared magnitudes from the bf16 tiles (consistent with the bf16 Gram) ----
    if (tid < 128) {
        const unsigned short* src = (tid < 64) ? Ab : Bb;
        int row = tid & 63;
        float m = 0.0f;
#pragma unroll
        for (int c = 0; c < 16; ++c) {
            bf16x8 v = *(const bf16x8*)((const char*)src + row * 256 + ((c ^ (row & 7)) << 4));
#pragma unroll
            for (int e = 0; e < 8; ++e) {
                float f = bf2f((unsigned short)v[e]);
                m = fmaf(f, f, m);
            }
        }
        if (tid < 64) magA[row] = m; else magB[row] = m;
    }
    __syncthreads();

    // ---- MFMA: each wave computes a 32x32 quadrant (2x2 fragments), K=128 in 4 steps ----
    const int l = tid & 63, w = tid >> 6;
    const int wr = w >> 1, wc = w & 1;
    const int l15 = l & 15, l4 = l >> 4;

    f32x4 acc[2][2];
#pragma unroll
    for (int mi = 0; mi < 2; ++mi)
#pragma unroll
        for (int ni = 0; ni < 2; ++ni)
            acc[mi][ni] = (f32x4){0.0f, 0.0f, 0.0f, 0.0f};

#pragma unroll
    for (int ks = 0; ks < 4; ++ks) {
        int cch = ks * 4 + l4;                  // 16B chunk index = k-offset/8
        bf16x8 afr[2], bfr[2];
#pragma unroll
        for (int mi = 0; mi < 2; ++mi) {
            int row = wr * 32 + mi * 16 + l15;
            afr[mi] = *(const bf16x8*)((const char*)Ab + row * 256 + ((cch ^ (row & 7)) << 4));
        }
#pragma unroll
        for (int ni = 0; ni < 2; ++ni) {
            int row = wc * 32 + ni * 16 + l15;
            bfr[ni] = *(const bf16x8*)((const char*)Bb + row * 256 + ((cch ^ (row & 7)) << 4));
        }
#pragma unroll
        for (int mi = 0; mi < 2; ++mi)
#pragma unroll
            for (int ni = 0; ni < 2; ++ni)
                acc[mi][ni] = __builtin_amdgcn_mfma_f32_16x16x32_bf16(
                    afr[mi], bfr[ni], acc[mi][ni], 0, 0, 0);
    }

    // ---- epilogue: masked exp, per-lane row/col partials ----
    float rp[2][4] = {{0.f,0.f,0.f,0.f},{0.f,0.f,0.f,0.f}};
    float cp[2] = {0.f, 0.f};
#pragma unroll
    for (int mi = 0; mi < 2; ++mi)
#pragma unroll
        for (int ni = 0; ni < 2; ++ni)
#pragma unroll
            for (int j = 0; j < 4; ++j) {
                int rl = wr * 32 + mi * 16 + l4 * 4 + j;   // local row
                int cl = wc * 32 + ni * 16 + l15;          // local col
                float s = acc[mi][ni][j];
                if (labA[rl] != labB[cl]) {
                    float d2 = fmaxf(magA[rl] + magB[cl] - 2.0f * s, 0.0f);
                    float t = __expf(MARGIN_F - sqrtf(d2));
                    rp[mi][j] += t;
                    cp[ni] += t;
                }
            }

#pragma unroll
    for (int mi = 0; mi < 2; ++mi)
#pragma unroll
        for (int j = 0; j < 4; ++j)
            rowred[wr * 32 + mi * 16 + l4 * 4 + j][wc * 16 + l15] = rp[mi][j];
#pragma unroll
    for (int ni = 0; ni < 2; ++ni)
        colred[wc * 32 + ni * 16 + l15][wr * 4 + l4] = cp[ni];
    __syncthreads();

    if (tid < 64) {
        float s = 0.0f;
#pragma unroll
        for (int x = 0; x < 32; ++x) s += rowred[tid][x];
        atomicAdd(&g_row_neg[biBase + tid], s);
    } else if (tid < 128 && bj > bi) {
        int t2 = tid - 64;
        float s = 0.0f;
#pragma unroll
        for (int x = 0; x < 8; ++x) s += colred[t2][x];
        atomicAdd(&g_row_neg[bjBase + t2], s);
    }
}

// ---------------- positive-pair hinge loss + fused final division ----------------
__global__ __launch_bounds__(256) void loss_kernel(const float* __restrict__ X,
                                                   float* __restrict__ out) {
    const int c = blockIdx.x;
    const int n = g_hist[c];
    const int base = g_offs[c];
    const long long P = (long long)n * (n - 1) / 2;
    float lacc = 0.0f;

    for (long long p = threadIdx.x + (long long)blockIdx.y * 256; p < P; p += 1024) {
        // decode (a,b), a<b, from linear upper-triangular index p
        float nf = (float)n;
        float pf = (float)p;
        int a = (int)((nf - 0.5f) - sqrtf((nf - 0.5f) * (nf - 0.5f) - 2.0f * pf));
        if (a < 0) a = 0;
        if (a > n - 2) a = n - 2;
        auto cum = [&](int aa) -> long long {
            return (long long)aa * (n - 1) - (long long)aa * (aa - 1) / 2;
        };
        while (cum(a + 1) <= p) ++a;
        while (cum(a) > p) --a;
        int b = (int)(p - cum(a)) + a + 1;

        int ia = g_order[base + a], ib = g_order[base + b];
        const float4* xa = (const float4*)(X + (size_t)ia * D);
        const float4* xb = (const float4*)(X + (size_t)ib * D);
        float d2 = 0.0f;
#pragma unroll
        for (int k = 0; k < D / 4; ++k) {
            float4 u = xa[k]; float4 v = xb[k];
            float dx = u.x - v.x, dy = u.y - v.y, dz = u.z - v.z, dw = u.w - v.w;
            d2 = fmaf(dx, dx, d2); d2 = fmaf(dy, dy, d2);
            d2 = fmaf(dz, dz, d2); d2 = fmaf(dw, dw, d2);
        }
        float dist = sqrtf(d2);
        float ln = logf(g_row_neg[ia] + g_row_neg[ib]);
        float h = fmaxf(ln + dist, 0.0f);
        lacc = fmaf(h, h, lacc);
    }

    for (int off = 32; off > 0; off >>= 1) lacc += __shfl_down(lacc, off);
    __shared__ float ws[4];
    int lane = threadIdx.x & 63, w = threadIdx.x >> 6;
    if (lane == 0) ws[w] = lacc;
    __syncthreads();
    if (threadIdx.x == 0) {
        atomicAdd(&g_acc, ws[0] + ws[1] + ws[2] + ws[3]);
        __threadfence();
        int d = atomicAdd(&g_done, 1);
        if (d == LOSS_BLOCKS - 1) {            // last block finishes: fused final division
            __threadfence();
            float total = atomicAdd(&g_acc, 0.0f);   // device-scope coherent read
            out[0] = total / (2.0f * (float)g_counter);
        }
    }
}

extern "C" void kernel_launch(void* const* d_in, const int* in_sizes, int n_in,
                              void* d_out, int out_size, void* d_ws, size_t ws_size,
                              hipStream_t stream) {
    const float* X = (const float*)d_in[0];
    const int* T = (const int*)d_in[1];
    float* out = (float*)d_out;
    (void)d_ws; (void)ws_size;

    prep_kernel<<<dim3(1), dim3(1024), 0, stream>>>(T);
    rowneg_kernel<<<dim3(64, 64), dim3(256), 0, stream>>>(X, T);
    loss_kernel<<<dim3(64, 4), dim3(256), 0, stream>>>(X, out);
}